// Round 22
// baseline (228.332 us; speedup 1.0000x reference)
//
#include <hip/hip_runtime.h>

#define FDIM 64
#define ECAP 512         // staged edges per tile in k_layer (mean 160)
#define NBK_SHIFT 8      // 256 nodes per coarse bucket
#define BCAP 4096        // staged edges per bucket in k_blocal (mean 2560)
#define CHUNK 4096       // edges per k_bgroup block (245 blocks ~ 1/CU)

typedef unsigned int uint32;
typedef unsigned short ushort16;
typedef __attribute__((ext_vector_type(8))) short bf8v;   // 8 bf16 in 4 VGPRs
typedef __attribute__((ext_vector_type(4))) float f4v;    // 4 fp32

static inline size_t align_up(size_t v) { return (v + 255) & ~(size_t)255; }

__device__ __forceinline__ float bcastf(float v, int l) {
    return __int_as_float(__builtin_amdgcn_readlane(__float_as_int(v), l));
}
__device__ __forceinline__ float bf_lo(uint32 u) { return __uint_as_float(u << 16); }
__device__ __forceinline__ float bf_hi(uint32 u) { return __uint_as_float(u & 0xFFFF0000u); }
__device__ __forceinline__ unsigned short f2bf(float f) {   // RNE
    uint32 u = __float_as_uint(f);
    return (unsigned short)((u + 0x7FFFu + ((u >> 16) & 1u)) >> 16);
}
__device__ __forceinline__ float bf2f(unsigned short s) {
    return __uint_as_float(((uint32)s) << 16);
}

// ---------------- CSR build: 1-digit radix with LDS write-regrouping --------

// per-block LDS histogram of buckets; also does the x->bf16 convert (fused)
__global__ __launch_bounds__(256) void k_bhist(const int* __restrict__ dst,
                                               int* __restrict__ bcount, int E, int nb,
                                               const float* __restrict__ xin,
                                               ushort16* __restrict__ xbf, long n4) {
    __shared__ int h[512];
    for (int i = threadIdx.x; i < nb; i += 256) h[i] = 0;
    __syncthreads();
    long stride = (long)gridDim.x * blockDim.x;
    long tid = (long)blockIdx.x * blockDim.x + threadIdx.x;
    // fused fp32 -> bf16 convert (independent of histogram)
    for (long i = tid; i < n4; i += stride) {
        float4 v = ((const float4*)xin)[i];
        uint2 o;
        o.x = (uint32)f2bf(v.x) | ((uint32)f2bf(v.y) << 16);
        o.y = (uint32)f2bf(v.z) | ((uint32)f2bf(v.w) << 16);
        ((uint2*)xbf)[i] = o;
    }
    for (long e = tid; e < E; e += stride)
        atomicAdd(&h[dst[e] >> NBK_SHIFT], 1);
    __syncthreads();
    for (int i = threadIdx.x; i < nb; i += 256)
        if (h[i]) atomicAdd(&bcount[i], h[i]);
}

__global__ __launch_bounds__(512) void k_bscan(const int* __restrict__ bcount,
                                               int* __restrict__ bbase,
                                               int* __restrict__ bcursor, int nb,
                                               int* __restrict__ rowstart, int n, int E) {
    __shared__ int sh[512];
    int t = threadIdx.x;
    int v = (t < nb) ? bcount[t] : 0;
    sh[t] = v;
    __syncthreads();
    for (int off = 1; off < 512; off <<= 1) {
        int a = (t >= off) ? sh[t - off] : 0;
        __syncthreads();
        sh[t] += a;
        __syncthreads();
    }
    if (t < nb) { int ex = sh[t] - v; bbase[t] = ex; bcursor[t] = ex; }
    if (t == 0) { bbase[nb] = E; rowstart[n] = E; }
}

__global__ __launch_bounds__(1024) void k_bgroup(const int* __restrict__ src,
                                                 const int* __restrict__ dst,
                                                 int* __restrict__ bcursor,
                                                 uint32* __restrict__ ebuf, int E, int nb) {
    __shared__ uint32 sorted[CHUNK];          // 16KB
    __shared__ unsigned short bop[CHUNK];     // 8KB
    __shared__ int hist[512];
    __shared__ int gbase[512];
    __shared__ int cur[512];
    __shared__ int sh[512];
    int c0 = blockIdx.x * CHUNK;
    int cend = c0 + CHUNK; if (cend > E) cend = E;
    int cnt = cend - c0;
    int t = threadIdx.x;
    for (int i = t; i < nb; i += 1024) hist[i] = 0;
    __syncthreads();
    for (int i = t; i < cnt; i += 1024)
        atomicAdd(&hist[dst[c0 + i] >> NBK_SHIFT], 1);
    __syncthreads();
    int v = 0;
    if (t < 512) { v = (t < nb) ? hist[t] : 0; sh[t] = v; }
    __syncthreads();
    for (int off = 1; off < 512; off <<= 1) {
        int a = (t >= off && t < 512) ? sh[t - off] : 0;
        __syncthreads();
        if (t < 512) sh[t] += a;
        __syncthreads();
    }
    if (t < nb) {
        int lofs = sh[t] - v;
        cur[t] = lofs;
        hist[t] = lofs;
        gbase[t] = v ? atomicAdd(&bcursor[t], v) : 0;
    }
    __syncthreads();
    for (int i = t; i < cnt; i += 1024) {
        int d = dst[c0 + i], s = src[c0 + i];
        int b = d >> NBK_SHIFT;
        int p = atomicAdd(&cur[b], 1);
        sorted[p] = ((uint32)(d & ((1 << NBK_SHIFT) - 1)) << 24) | (uint32)s;
        bop[p] = (unsigned short)b;
    }
    __syncthreads();
    for (int i = t; i < cnt; i += 1024) {
        int b = bop[i];
        ebuf[gbase[b] + (i - hist[b])] = sorted[i];
    }
}

__global__ __launch_bounds__(512) void k_blocal(const uint32* __restrict__ ebuf,
                                                const int* __restrict__ bbase,
                                                int* __restrict__ rowstart,
                                                int* __restrict__ adj, int n) {
    __shared__ uint32 raw[BCAP];
    __shared__ int srt[BCAP];
    __shared__ int hist[257];
    __shared__ int cur[256];
    int b = blockIdx.x;
    int t = threadIdx.x;
    int lo = bbase[b], hi = bbase[b + 1];
    int cnt = hi - lo;
    for (int i = t; i < 257; i += 512) hist[i] = 0;
    __syncthreads();
    if (cnt <= BCAP) {
        for (int i = t; i < cnt; i += 512) {
            uint32 v = ebuf[lo + i];
            raw[i] = v;
            atomicAdd(&hist[(v >> 24) + 1], 1);
        }
        __syncthreads();
        for (int off = 1; off < 256; off <<= 1) {
            int a = (t >= off && t < 256) ? hist[t + 1 - off] : 0;
            __syncthreads();
            if (t < 256) hist[t + 1] += a;
            __syncthreads();
        }
        if (t < 256) cur[t] = hist[t];
        __syncthreads();
        for (int i = t; i < cnt; i += 512) {
            uint32 v = raw[i];
            int p = atomicAdd(&cur[v >> 24], 1);
            srt[p] = (int)(v & 0xFFFFFF);
        }
        __syncthreads();
        for (int i = t; i < cnt; i += 512) adj[lo + i] = srt[i];
    } else {
        for (int i = t; i < cnt; i += 512) {
            uint32 v = ebuf[lo + i];
            atomicAdd(&hist[(v >> 24) + 1], 1);
        }
        __syncthreads();
        for (int off = 1; off < 256; off <<= 1) {
            int a = (t >= off && t < 256) ? hist[t + 1 - off] : 0;
            __syncthreads();
            if (t < 256) hist[t + 1] += a;
            __syncthreads();
        }
        if (t < 256) cur[t] = hist[t];
        __syncthreads();
        for (int i = t; i < cnt; i += 512) {
            uint32 v = ebuf[lo + i];
            int p = atomicAdd(&cur[v >> 24], 1);
            adj[lo + p] = (int)(v & 0xFFFFFF);
        }
    }
    if (t < 256) {
        int node = (b << NBK_SHIFT) + t;
        if (node < n) rowstart[node] = lo + hist[t];
    }
}

// ---------------- fused layer via MFMA, bf16 h, LDS-staged adj ----------------
// 1024-thread blocks (16 waves), ONE tile (16 nodes) per wave, 4-edge unroll
// (measured-best shape: R15/R18/R21 all ~43.3-43.7us; 8-edge unroll spills,
// min-waves launch_bounds caps VGPR at 32 and spills — both verified bad).
// C layout (verified): col = lane&15 (out-feat), row = kg*4 + reg (node).

__global__ __launch_bounds__(1024) void k_layer(
    const ushort16* __restrict__ Hbf, const int* __restrict__ rowstart,
    const int* __restrict__ adj, const float* __restrict__ Wr,
    const float* __restrict__ Wo, const float* __restrict__ bias,
    const float* __restrict__ slope_p, ushort16* __restrict__ HbfOut,
    int n, int do_prelu)
{
    __shared__ unsigned short wh[64 * 128];   // 16KB  W_cat hi, swizzled
    __shared__ unsigned short wl[64 * 128];   // 16KB  W_cat lo
    __shared__ int eidx[16][ECAP];            // 32KB  per-wave staged edges

    for (int e = threadIdx.x; e < 64 * 128; e += 1024) {
        int nn = e >> 7;
        int k  = e & 127;
        float v = (k < 64) ? Wr[k * 64 + nn] : Wo[(k - 64) * 64 + nn];
        unsigned short hi = f2bf(v);
        unsigned short lo = f2bf(v - bf2f(hi));
        int boff = nn * 256 + ((k * 2) ^ ((nn & 7) << 4));
        wh[boff >> 1] = hi;
        wl[boff >> 1] = lo;
    }
    __syncthreads();

    int lane  = threadIdx.x & 63;
    int l15   = lane & 15;
    int kg    = lane >> 4;
    int koff  = kg * 8;                       // ushort offset of first chunk
    int wslot = threadIdx.x >> 6;             // 0..15
    int wid  = (blockIdx.x * blockDim.x + threadIdx.x) >> 6;
    int nw   = (gridDim.x * blockDim.x) >> 6;
    int ntiles = (n + 15) >> 4;
    float slope = do_prelu ? slope_p[0] : 1.0f;
    float bv0 = bias[l15], bv1 = bias[16 + l15], bv2 = bias[32 + l15], bv3 = bias[48 + l15];

    for (int t = wid; t < ntiles; t += nw) {
        int base16 = t * 16;
        int node = base16 + l15;
        bool valid = node < n;
        int s0 = valid ? rowstart[node] : 0;
        int s1 = valid ? rowstart[node + 1] : 0;
        int ebase = __builtin_amdgcn_readlane(s0, 0);
        int eend  = __builtin_amdgcn_readlane(s1, 15);
        if (!valid) { s0 = 0; s1 = 0; }
        if (base16 + 16 > n) eend = rowstart[n];
        int ecount = eend - ebase;

        // stage tile's edges (coalesced); only ds (lgkm) must drain
        int cap = ecount < ECAP ? ecount : ECAP;
        for (int i = lane; i < cap; i += 64) eidx[wslot][i] = adj[ebase + i];
        asm volatile("s_waitcnt lgkmcnt(0)" ::: "memory");

        // self row loads AFTER the barrier: latency hides under gather loop
        int4 su = {0, 0, 0, 0}, sv = {0, 0, 0, 0};
        if (valid) {
            const ushort16* sp = Hbf + ((long)node << 6);
            su = *(const int4*)(sp + koff);
            sv = *(const int4*)(sp + koff + 32);
        }

        float acc[16];
#pragma unroll
        for (int i = 0; i < 16; i++) acc[i] = 0.f;

#define ACC8(UU, BASE) \
        acc[BASE+0] += bf_lo(UU.x); acc[BASE+1] += bf_hi(UU.x); \
        acc[BASE+2] += bf_lo(UU.y); acc[BASE+3] += bf_hi(UU.y); \
        acc[BASE+4] += bf_lo(UU.z); acc[BASE+5] += bf_hi(UU.z); \
        acc[BASE+6] += bf_lo(UU.w); acc[BASE+7] += bf_hi(UU.w);

        if (ecount <= ECAP) {
            int ls0 = s0 - ebase, ls1 = s1 - ebase;
            const int* ix = eidx[wslot];
            int j = ls0;
            for (; j + 4 <= ls1; j += 4) {     // 8 x 16B row loads in flight
                long r0 = ix[j], r1 = ix[j + 1], r2 = ix[j + 2], r3 = ix[j + 3];
                const ushort16* p0 = Hbf + (r0 << 6);
                const ushort16* p1 = Hbf + (r1 << 6);
                const ushort16* p2 = Hbf + (r2 << 6);
                const ushort16* p3 = Hbf + (r3 << 6);
                int4 u0 = *(const int4*)(p0 + koff), v0 = *(const int4*)(p0 + koff + 32);
                int4 u1 = *(const int4*)(p1 + koff), v1 = *(const int4*)(p1 + koff + 32);
                int4 u2 = *(const int4*)(p2 + koff), v2 = *(const int4*)(p2 + koff + 32);
                int4 u3 = *(const int4*)(p3 + koff), v3 = *(const int4*)(p3 + koff + 32);
                ACC8(u0, 0)  ACC8(u1, 0)  ACC8(u2, 0)  ACC8(u3, 0)
                ACC8(v0, 8)  ACC8(v1, 8)  ACC8(v2, 8)  ACC8(v3, 8)
            }
            for (; j < ls1; j++) {
                long r0 = ix[j];
                const ushort16* p0 = Hbf + (r0 << 6);
                int4 u0 = *(const int4*)(p0 + koff), v0 = *(const int4*)(p0 + koff + 32);
                ACC8(u0, 0)  ACC8(v0, 8)
            }
        } else {                               // overflow fallback
            for (int e = s0; e < s1; e++) {
                long r0 = adj[e];
                const ushort16* p0 = Hbf + (r0 << 6);
                int4 u0 = *(const int4*)(p0 + koff), v0 = *(const int4*)(p0 + koff + 32);
                ACC8(u0, 0)  ACC8(v0, 8)
            }
        }
#undef ACC8

        // A-fragments: kb 0,1 = agg (hi/lo split), kb 2,3 = self (bf16 exact)
        bf8v ah[4], al[2];
#pragma unroll
        for (int kb = 0; kb < 2; kb++) {
#pragma unroll
            for (int j = 0; j < 8; j++) {
                float v = acc[kb * 8 + j];
                unsigned short h = f2bf(v);
                ah[kb][j] = (short)h;
                al[kb][j] = (short)f2bf(v - bf2f(h));
            }
        }
        ah[2] = __builtin_bit_cast(bf8v, su);
        ah[3] = __builtin_bit_cast(bf8v, sv);

        f4v C[4];
        C[0] = (f4v){bv0, bv0, bv0, bv0};
        C[1] = (f4v){bv1, bv1, bv1, bv1};
        C[2] = (f4v){bv2, bv2, bv2, bv2};
        C[3] = (f4v){bv3, bv3, bv3, bv3};

#pragma unroll
        for (int kb = 0; kb < 4; kb++) {
#pragma unroll
            for (int nt = 0; nt < 4; nt++) {
                int row = nt * 16 + l15;
                int boff = row * 256 + (((kb * 32 + kg * 8) * 2) ^ ((l15 & 7) << 4));
                bf8v bh = *(const bf8v*)((const char*)wh + boff);
                bf8v bl = *(const bf8v*)((const char*)wl + boff);
                C[nt] = __builtin_amdgcn_mfma_f32_16x16x32_bf16(ah[kb], bh, C[nt], 0, 0, 0);
                if (kb < 2)
                    C[nt] = __builtin_amdgcn_mfma_f32_16x16x32_bf16(al[kb], bh, C[nt], 0, 0, 0);
                C[nt] = __builtin_amdgcn_mfma_f32_16x16x32_bf16(ah[kb], bl, C[nt], 0, 0, 0);
            }
        }

        // epilogue: C row = node (kg*4 + r), col = out-feat (nt*16 + l15)
#pragma unroll
        for (int r = 0; r < 4; r++) {
            int onode = base16 + kg * 4 + r;
            if (onode < n) {
#pragma unroll
                for (int nt = 0; nt < 4; nt++) {
                    float v = C[nt][r];
                    v = v >= 0.f ? v : slope * v;
                    HbfOut[((long)onode << 6) + nt * 16 + l15] = f2bf(v);
                }
            }
        }
    }
}

// ---------------- fused mean-pool + head: one block per graph --------------
// Graph g's nodes are CONTIGUOUS (batch sorted): binary-search the range,
// pool with 8 waves of coalesced reads (no atomics), LDS-reduce, wave 0 GEMV.

__global__ __launch_bounds__(512) void k_headpool(
    const ushort16* __restrict__ h, const int* __restrict__ batch, int n,
    const float* __restrict__ W0, const float* __restrict__ b0,
    const float* __restrict__ W1, const float* __restrict__ b1,
    float* __restrict__ out, int OUT)
{
    __shared__ float red[8][FDIM];
    int g = blockIdx.x;
    int lane  = threadIdx.x & 63;
    int wslot = threadIdx.x >> 6;             // 0..7

    // [start, end) of graph g in sorted batch (uniform across block)
    int lo = 0, hi = n;
    while (lo < hi) { int m = (lo + hi) >> 1; if (batch[m] < g) lo = m + 1; else hi = m; }
    int start = lo;
    int lo2 = lo, hi2 = n;
    while (lo2 < hi2) { int m = (lo2 + hi2) >> 1; if (batch[m] <= g) lo2 = m + 1; else hi2 = m; }
    int end = lo2;

    float acc = 0.f;
    for (int i = start + wslot; i < end; i += 8)
        acc += bf2f(h[(long)i * FDIM + lane]);
    red[wslot][lane] = acc;
    __syncthreads();

    if (wslot == 0) {
        float p = ((red[0][lane] + red[1][lane]) + (red[2][lane] + red[3][lane]))
                + ((red[4][lane] + red[5][lane]) + (red[6][lane] + red[7][lane]));
        float c = (float)(end - start);
        if (c < 1.f) c = 1.f;
        p /= c;

        float h0 = 0.f, h1 = 0.f, h2 = 0.f, h3 = 0.f;
#pragma unroll
        for (int k = 0; k < FDIM; k += 4) {
            h0 += bcastf(p, k + 0) * W0[(k + 0) * FDIM + lane];
            h1 += bcastf(p, k + 1) * W0[(k + 1) * FDIM + lane];
            h2 += bcastf(p, k + 2) * W0[(k + 2) * FDIM + lane];
            h3 += bcastf(p, k + 3) * W0[(k + 3) * FDIM + lane];
        }
        float hid = b0[lane] + ((h0 + h1) + (h2 + h3));
        for (int o = 0; o < OUT; o++) {
            float part = hid * W1[lane * OUT + o];
#pragma unroll
            for (int m = 32; m >= 1; m >>= 1) part += __shfl_xor(part, m, 64);
            if (lane == 0) out[g * OUT + o] = part + b1[o];
        }
    }
}

extern "C" void kernel_launch(void* const* d_in, const int* in_sizes, int n_in,
                              void* d_out, int out_size, void* d_ws, size_t ws_size,
                              hipStream_t stream) {
    const float* x     = (const float*)d_in[0];
    const int*   ei    = (const int*)d_in[1];
    const int*   batch = (const int*)d_in[2];
    const float* W1r = (const float*)d_in[3];
    const float* b1  = (const float*)d_in[4];
    const float* W1o = (const float*)d_in[5];
    const float* W2r = (const float*)d_in[6];
    const float* b2  = (const float*)d_in[7];
    const float* W2o = (const float*)d_in[8];
    const float* W3r = (const float*)d_in[9];
    const float* b3  = (const float*)d_in[10];
    const float* W3o = (const float*)d_in[11];
    const float* a1  = (const float*)d_in[12];
    const float* a2  = (const float*)d_in[13];
    const float* Wl0 = (const float*)d_in[14];
    const float* bl0 = (const float*)d_in[15];
    const float* Wl1 = (const float*)d_in[16];
    const float* bl1 = (const float*)d_in[17];

    int N = in_sizes[0] / FDIM;
    int E = in_sizes[1] / 2;
    int OUT = in_sizes[17];
    int G = out_size / OUT;
    int nb = (N + 255) >> NBK_SHIFT;          // 256-node buckets

    const int* src = ei;
    const int* dst = ei + E;

    // workspace layout
    char* w = (char*)d_ws;
    int* rowstart = (int*)w;              w += align_up((size_t)(N + 1) * 4);
    int* adj      = (int*)w;              w += align_up((size_t)E * 4 + 256);
    uint32* ebuf  = (uint32*)w;           w += align_up((size_t)E * 4);
    int* bbase    = (int*)w;              w += align_up((size_t)(nb + 1) * 4);
    int* bcursor  = (int*)w;              w += align_up((size_t)nb * 4);
    ushort16* xbf = (ushort16*)w;         w += align_up((size_t)N * FDIM * 2);
    ushort16* hb1 = (ushort16*)w;         w += align_up((size_t)N * FDIM * 2);
    ushort16* hb2 = (ushort16*)w;         w += align_up((size_t)N * FDIM * 2);
    int* bcount   = (int*)w;              w += align_up(512 * 4);

    hipMemsetAsync(bcount, 0, 512 * 4, stream);

    // CSR build (radix pass with LDS write-regrouping); bhist also converts x
    k_bhist<<<512, 256, 0, stream>>>(dst, bcount, E, nb, x, xbf, (long)N * FDIM / 4);
    k_bscan<<<1, 512, 0, stream>>>(bcount, bbase, bcursor, nb, rowstart, N, E);
    int nchunks = (E + CHUNK - 1) / CHUNK;
    k_bgroup<<<nchunks, 1024, 0, stream>>>(src, dst, bcursor, ebuf, E, nb);
    k_blocal<<<nb, 512, 0, stream>>>(ebuf, bbase, rowstart, adj, N);

    // MFMA fused layers: 16 waves/block, 1 tile/wave (measured-best shape);
    // layer 3 writes into hb1 (dead after layer 2)
    int ntiles = (N + 15) / 16;
    int layerGrid = (ntiles + 15) / 16;        // 391 blocks of 1024 threads
    k_layer<<<layerGrid, 1024, 0, stream>>>(xbf, rowstart, adj, W1r, W1o, b1, a1, hb1, N, 1);
    k_layer<<<layerGrid, 1024, 0, stream>>>(hb1, rowstart, adj, W2r, W2o, b2, a2, hb2, N, 1);
    k_layer<<<layerGrid, 1024, 0, stream>>>(hb2, rowstart, adj, W3r, W3o, b3, nullptr, hb1, N, 0);

    // fused mean-pool + head (contiguous per-graph ranges, no atomics)
    k_headpool<<<G, 512, 0, stream>>>(hb1, batch, N, Wl0, bl0, Wl1, bl1, (float*)d_out, OUT);
}

// Round 23
// 191.983 us; speedup vs baseline: 1.1893x; 1.1893x over previous
//
#include <hip/hip_runtime.h>

#define FDIM 64
#define POOL_CHUNK 32    // nodes per wave in pooling
#define ECAP 512         // staged edges per tile in k_layer (mean 160)
#define NBK_SHIFT 8      // 256 nodes per coarse bucket
#define BCAP 4096        // staged edges per bucket in k_blocal (mean 2560)
#define CHUNK 4096       // edges per k_bgroup block (245 blocks ~ 1/CU)

typedef unsigned int uint32;
typedef unsigned short ushort16;
typedef __attribute__((ext_vector_type(8))) short bf8v;   // 8 bf16 in 4 VGPRs
typedef __attribute__((ext_vector_type(4))) float f4v;    // 4 fp32

static inline size_t align_up(size_t v) { return (v + 255) & ~(size_t)255; }

__device__ __forceinline__ float bcastf(float v, int l) {
    return __int_as_float(__builtin_amdgcn_readlane(__float_as_int(v), l));
}
__device__ __forceinline__ float bf_lo(uint32 u) { return __uint_as_float(u << 16); }
__device__ __forceinline__ float bf_hi(uint32 u) { return __uint_as_float(u & 0xFFFF0000u); }
__device__ __forceinline__ unsigned short f2bf(float f) {   // RNE
    uint32 u = __float_as_uint(f);
    return (unsigned short)((u + 0x7FFFu + ((u >> 16) & 1u)) >> 16);
}
__device__ __forceinline__ float bf2f(unsigned short s) {
    return __uint_as_float(((uint32)s) << 16);
}

// ---------------- CSR build: 1-digit radix with LDS write-regrouping --------

// per-block LDS histogram of buckets; also does the x->bf16 convert (fused)
__global__ __launch_bounds__(256) void k_bhist(const int* __restrict__ dst,
                                               int* __restrict__ bcount, int E, int nb,
                                               const float* __restrict__ xin,
                                               ushort16* __restrict__ xbf, long n4) {
    __shared__ int h[512];
    for (int i = threadIdx.x; i < nb; i += 256) h[i] = 0;
    __syncthreads();
    long stride = (long)gridDim.x * blockDim.x;
    long tid = (long)blockIdx.x * blockDim.x + threadIdx.x;
    // fused fp32 -> bf16 convert (independent of histogram)
    for (long i = tid; i < n4; i += stride) {
        float4 v = ((const float4*)xin)[i];
        uint2 o;
        o.x = (uint32)f2bf(v.x) | ((uint32)f2bf(v.y) << 16);
        o.y = (uint32)f2bf(v.z) | ((uint32)f2bf(v.w) << 16);
        ((uint2*)xbf)[i] = o;
    }
    for (long e = tid; e < E; e += stride)
        atomicAdd(&h[dst[e] >> NBK_SHIFT], 1);
    __syncthreads();
    for (int i = threadIdx.x; i < nb; i += 256)
        if (h[i]) atomicAdd(&bcount[i], h[i]);
}

__global__ __launch_bounds__(512) void k_bscan(const int* __restrict__ bcount,
                                               int* __restrict__ bbase,
                                               int* __restrict__ bcursor, int nb,
                                               int* __restrict__ rowstart, int n, int E) {
    __shared__ int sh[512];
    int t = threadIdx.x;
    int v = (t < nb) ? bcount[t] : 0;
    sh[t] = v;
    __syncthreads();
    for (int off = 1; off < 512; off <<= 1) {
        int a = (t >= off) ? sh[t - off] : 0;
        __syncthreads();
        sh[t] += a;
        __syncthreads();
    }
    if (t < nb) { int ex = sh[t] - v; bbase[t] = ex; bcursor[t] = ex; }
    if (t == 0) { bbase[nb] = E; rowstart[n] = E; }
}

__global__ __launch_bounds__(1024) void k_bgroup(const int* __restrict__ src,
                                                 const int* __restrict__ dst,
                                                 int* __restrict__ bcursor,
                                                 uint32* __restrict__ ebuf, int E, int nb) {
    __shared__ uint32 sorted[CHUNK];          // 16KB
    __shared__ unsigned short bop[CHUNK];     // 8KB
    __shared__ int hist[512];
    __shared__ int gbase[512];
    __shared__ int cur[512];
    __shared__ int sh[512];
    int c0 = blockIdx.x * CHUNK;
    int cend = c0 + CHUNK; if (cend > E) cend = E;
    int cnt = cend - c0;
    int t = threadIdx.x;
    for (int i = t; i < nb; i += 1024) hist[i] = 0;
    __syncthreads();
    for (int i = t; i < cnt; i += 1024)
        atomicAdd(&hist[dst[c0 + i] >> NBK_SHIFT], 1);
    __syncthreads();
    int v = 0;
    if (t < 512) { v = (t < nb) ? hist[t] : 0; sh[t] = v; }
    __syncthreads();
    for (int off = 1; off < 512; off <<= 1) {
        int a = (t >= off && t < 512) ? sh[t - off] : 0;
        __syncthreads();
        if (t < 512) sh[t] += a;
        __syncthreads();
    }
    if (t < nb) {
        int lofs = sh[t] - v;
        cur[t] = lofs;
        hist[t] = lofs;
        gbase[t] = v ? atomicAdd(&bcursor[t], v) : 0;
    }
    __syncthreads();
    for (int i = t; i < cnt; i += 1024) {
        int d = dst[c0 + i], s = src[c0 + i];
        int b = d >> NBK_SHIFT;
        int p = atomicAdd(&cur[b], 1);
        sorted[p] = ((uint32)(d & ((1 << NBK_SHIFT) - 1)) << 24) | (uint32)s;
        bop[p] = (unsigned short)b;
    }
    __syncthreads();
    for (int i = t; i < cnt; i += 1024) {
        int b = bop[i];
        ebuf[gbase[b] + (i - hist[b])] = sorted[i];
    }
}

__global__ __launch_bounds__(512) void k_blocal(const uint32* __restrict__ ebuf,
                                                const int* __restrict__ bbase,
                                                int* __restrict__ rowstart,
                                                int* __restrict__ adj, int n) {
    __shared__ uint32 raw[BCAP];
    __shared__ int srt[BCAP];
    __shared__ int hist[257];
    __shared__ int cur[256];
    int b = blockIdx.x;
    int t = threadIdx.x;
    int lo = bbase[b], hi = bbase[b + 1];
    int cnt = hi - lo;
    for (int i = t; i < 257; i += 512) hist[i] = 0;
    __syncthreads();
    if (cnt <= BCAP) {
        for (int i = t; i < cnt; i += 512) {
            uint32 v = ebuf[lo + i];
            raw[i] = v;
            atomicAdd(&hist[(v >> 24) + 1], 1);
        }
        __syncthreads();
        for (int off = 1; off < 256; off <<= 1) {
            int a = (t >= off && t < 256) ? hist[t + 1 - off] : 0;
            __syncthreads();
            if (t < 256) hist[t + 1] += a;
            __syncthreads();
        }
        if (t < 256) cur[t] = hist[t];
        __syncthreads();
        for (int i = t; i < cnt; i += 512) {
            uint32 v = raw[i];
            int p = atomicAdd(&cur[v >> 24], 1);
            srt[p] = (int)(v & 0xFFFFFF);
        }
        __syncthreads();
        for (int i = t; i < cnt; i += 512) adj[lo + i] = srt[i];
    } else {
        for (int i = t; i < cnt; i += 512) {
            uint32 v = ebuf[lo + i];
            atomicAdd(&hist[(v >> 24) + 1], 1);
        }
        __syncthreads();
        for (int off = 1; off < 256; off <<= 1) {
            int a = (t >= off && t < 256) ? hist[t + 1 - off] : 0;
            __syncthreads();
            if (t < 256) hist[t + 1] += a;
            __syncthreads();
        }
        if (t < 256) cur[t] = hist[t];
        __syncthreads();
        for (int i = t; i < cnt; i += 512) {
            uint32 v = ebuf[lo + i];
            int p = atomicAdd(&cur[v >> 24], 1);
            adj[lo + p] = (int)(v & 0xFFFFFF);
        }
    }
    if (t < 256) {
        int node = (b << NBK_SHIFT) + t;
        if (node < n) rowstart[node] = lo + hist[t];
    }
}

// ---------------- fused layer via MFMA, bf16 h, LDS-staged adj ----------------
// 1024-thread blocks (16 waves), ONE tile (16 nodes) per wave, 4-edge unroll
// (measured-best shape: R15/R18/R21 all ~43.3-43.7us; 8-edge unroll spills,
// min-waves launch_bounds caps VGPR at 32 and spills — both verified bad).
// C layout (verified): col = lane&15 (out-feat), row = kg*4 + reg (node).

__global__ __launch_bounds__(1024) void k_layer(
    const ushort16* __restrict__ Hbf, const int* __restrict__ rowstart,
    const int* __restrict__ adj, const float* __restrict__ Wr,
    const float* __restrict__ Wo, const float* __restrict__ bias,
    const float* __restrict__ slope_p, ushort16* __restrict__ HbfOut,
    int n, int do_prelu)
{
    __shared__ unsigned short wh[64 * 128];   // 16KB  W_cat hi, swizzled
    __shared__ unsigned short wl[64 * 128];   // 16KB  W_cat lo
    __shared__ int eidx[16][ECAP];            // 32KB  per-wave staged edges

    for (int e = threadIdx.x; e < 64 * 128; e += 1024) {
        int nn = e >> 7;
        int k  = e & 127;
        float v = (k < 64) ? Wr[k * 64 + nn] : Wo[(k - 64) * 64 + nn];
        unsigned short hi = f2bf(v);
        unsigned short lo = f2bf(v - bf2f(hi));
        int boff = nn * 256 + ((k * 2) ^ ((nn & 7) << 4));
        wh[boff >> 1] = hi;
        wl[boff >> 1] = lo;
    }
    __syncthreads();

    int lane  = threadIdx.x & 63;
    int l15   = lane & 15;
    int kg    = lane >> 4;
    int koff  = kg * 8;                       // ushort offset of first chunk
    int wslot = threadIdx.x >> 6;             // 0..15
    int wid  = (blockIdx.x * blockDim.x + threadIdx.x) >> 6;
    int nw   = (gridDim.x * blockDim.x) >> 6;
    int ntiles = (n + 15) >> 4;
    float slope = do_prelu ? slope_p[0] : 1.0f;
    float bv0 = bias[l15], bv1 = bias[16 + l15], bv2 = bias[32 + l15], bv3 = bias[48 + l15];

    for (int t = wid; t < ntiles; t += nw) {
        int base16 = t * 16;
        int node = base16 + l15;
        bool valid = node < n;
        int s0 = valid ? rowstart[node] : 0;
        int s1 = valid ? rowstart[node + 1] : 0;
        int ebase = __builtin_amdgcn_readlane(s0, 0);
        int eend  = __builtin_amdgcn_readlane(s1, 15);
        if (!valid) { s0 = 0; s1 = 0; }
        if (base16 + 16 > n) eend = rowstart[n];
        int ecount = eend - ebase;

        // stage tile's edges (coalesced); only ds (lgkm) must drain
        int cap = ecount < ECAP ? ecount : ECAP;
        for (int i = lane; i < cap; i += 64) eidx[wslot][i] = adj[ebase + i];
        asm volatile("s_waitcnt lgkmcnt(0)" ::: "memory");

        // self row loads AFTER the barrier: latency hides under gather loop
        int4 su = {0, 0, 0, 0}, sv = {0, 0, 0, 0};
        if (valid) {
            const ushort16* sp = Hbf + ((long)node << 6);
            su = *(const int4*)(sp + koff);
            sv = *(const int4*)(sp + koff + 32);
        }

        float acc[16];
#pragma unroll
        for (int i = 0; i < 16; i++) acc[i] = 0.f;

#define ACC8(UU, BASE) \
        acc[BASE+0] += bf_lo(UU.x); acc[BASE+1] += bf_hi(UU.x); \
        acc[BASE+2] += bf_lo(UU.y); acc[BASE+3] += bf_hi(UU.y); \
        acc[BASE+4] += bf_lo(UU.z); acc[BASE+5] += bf_hi(UU.z); \
        acc[BASE+6] += bf_lo(UU.w); acc[BASE+7] += bf_hi(UU.w);

        if (ecount <= ECAP) {
            int ls0 = s0 - ebase, ls1 = s1 - ebase;
            const int* ix = eidx[wslot];
            int j = ls0;
            for (; j + 4 <= ls1; j += 4) {     // 8 x 16B row loads in flight
                long r0 = ix[j], r1 = ix[j + 1], r2 = ix[j + 2], r3 = ix[j + 3];
                const ushort16* p0 = Hbf + (r0 << 6);
                const ushort16* p1 = Hbf + (r1 << 6);
                const ushort16* p2 = Hbf + (r2 << 6);
                const ushort16* p3 = Hbf + (r3 << 6);
                int4 u0 = *(const int4*)(p0 + koff), v0 = *(const int4*)(p0 + koff + 32);
                int4 u1 = *(const int4*)(p1 + koff), v1 = *(const int4*)(p1 + koff + 32);
                int4 u2 = *(const int4*)(p2 + koff), v2 = *(const int4*)(p2 + koff + 32);
                int4 u3 = *(const int4*)(p3 + koff), v3 = *(const int4*)(p3 + koff + 32);
                ACC8(u0, 0)  ACC8(u1, 0)  ACC8(u2, 0)  ACC8(u3, 0)
                ACC8(v0, 8)  ACC8(v1, 8)  ACC8(v2, 8)  ACC8(v3, 8)
            }
            for (; j < ls1; j++) {
                long r0 = ix[j];
                const ushort16* p0 = Hbf + (r0 << 6);
                int4 u0 = *(const int4*)(p0 + koff), v0 = *(const int4*)(p0 + koff + 32);
                ACC8(u0, 0)  ACC8(v0, 8)
            }
        } else {                               // overflow fallback
            for (int e = s0; e < s1; e++) {
                long r0 = adj[e];
                const ushort16* p0 = Hbf + (r0 << 6);
                int4 u0 = *(const int4*)(p0 + koff), v0 = *(const int4*)(p0 + koff + 32);
                ACC8(u0, 0)  ACC8(v0, 8)
            }
        }
#undef ACC8

        // A-fragments: kb 0,1 = agg (hi/lo split), kb 2,3 = self (bf16 exact)
        bf8v ah[4], al[2];
#pragma unroll
        for (int kb = 0; kb < 2; kb++) {
#pragma unroll
            for (int j = 0; j < 8; j++) {
                float v = acc[kb * 8 + j];
                unsigned short h = f2bf(v);
                ah[kb][j] = (short)h;
                al[kb][j] = (short)f2bf(v - bf2f(h));
            }
        }
        ah[2] = __builtin_bit_cast(bf8v, su);
        ah[3] = __builtin_bit_cast(bf8v, sv);

        f4v C[4];
        C[0] = (f4v){bv0, bv0, bv0, bv0};
        C[1] = (f4v){bv1, bv1, bv1, bv1};
        C[2] = (f4v){bv2, bv2, bv2, bv2};
        C[3] = (f4v){bv3, bv3, bv3, bv3};

#pragma unroll
        for (int kb = 0; kb < 4; kb++) {
#pragma unroll
            for (int nt = 0; nt < 4; nt++) {
                int row = nt * 16 + l15;
                int boff = row * 256 + (((kb * 32 + kg * 8) * 2) ^ ((l15 & 7) << 4));
                bf8v bh = *(const bf8v*)((const char*)wh + boff);
                bf8v bl = *(const bf8v*)((const char*)wl + boff);
                C[nt] = __builtin_amdgcn_mfma_f32_16x16x32_bf16(ah[kb], bh, C[nt], 0, 0, 0);
                if (kb < 2)
                    C[nt] = __builtin_amdgcn_mfma_f32_16x16x32_bf16(al[kb], bh, C[nt], 0, 0, 0);
                C[nt] = __builtin_amdgcn_mfma_f32_16x16x32_bf16(ah[kb], bl, C[nt], 0, 0, 0);
            }
        }

        // epilogue: C row = node (kg*4 + r), col = out-feat (nt*16 + l15)
#pragma unroll
        for (int r = 0; r < 4; r++) {
            int onode = base16 + kg * 4 + r;
            if (onode < n) {
#pragma unroll
                for (int nt = 0; nt < 4; nt++) {
                    float v = C[nt][r];
                    v = v >= 0.f ? v : slope * v;
                    HbfOut[((long)onode << 6) + nt * 16 + l15] = f2bf(v);
                }
            }
        }
    }
}

// ---------------- global mean pool (bf16 input, sorted batch) ----------------
// no cnt atomics: head computes counts by binary search

__global__ __launch_bounds__(256) void k_pool(const ushort16* __restrict__ h,
                                              const int* __restrict__ batch,
                                              float* __restrict__ sums, int n) {
    int wave = (blockIdx.x * 256 + threadIdx.x) >> 6;
    int lane = threadIdx.x & 63;
    int start = wave * POOL_CHUNK;
    if (start >= n) return;
    int end = start + POOL_CHUNK;
    if (end > n) end = n;
    int cur = batch[start];
    float acc = 0.f;
#pragma unroll 4
    for (int i = start; i < end; i++) {
        int g = batch[i];
        if (g != cur) {
            atomicAdd(&sums[cur * FDIM + lane], acc);
            acc = 0.f;
            cur = g;
        }
        acc += bf2f(h[(long)i * FDIM + lane]);
    }
    atomicAdd(&sums[cur * FDIM + lane], acc);
}

// ---------------- head: one wave per graph; cnt via binary search ----------

__global__ __launch_bounds__(64) void k_head(const float* __restrict__ sums,
                                             const int* __restrict__ batch, int n,
                                             const float* __restrict__ W0,
                                             const float* __restrict__ b0,
                                             const float* __restrict__ W1,
                                             const float* __restrict__ b1,
                                             float* __restrict__ out, int OUT) {
    int g = blockIdx.x;
    int lane = threadIdx.x;
    // count of nodes with batch == g (batch sorted); wave-uniform search
    int lo = 0, hi = n;
    while (lo < hi) { int m = (lo + hi) >> 1; if (batch[m] < g) lo = m + 1; else hi = m; }
    int lo2 = lo, hi2 = n;
    while (lo2 < hi2) { int m = (lo2 + hi2) >> 1; if (batch[m] <= g) lo2 = m + 1; else hi2 = m; }
    float c = (float)(lo2 - lo);
    if (c < 1.f) c = 1.f;
    float p = sums[g * FDIM + lane] / c;

    float h0 = 0.f, h1 = 0.f, h2 = 0.f, h3 = 0.f;
#pragma unroll
    for (int k = 0; k < FDIM; k += 4) {
        h0 += bcastf(p, k + 0) * W0[(k + 0) * FDIM + lane];
        h1 += bcastf(p, k + 1) * W0[(k + 1) * FDIM + lane];
        h2 += bcastf(p, k + 2) * W0[(k + 2) * FDIM + lane];
        h3 += bcastf(p, k + 3) * W0[(k + 3) * FDIM + lane];
    }
    float hid = b0[lane] + ((h0 + h1) + (h2 + h3));
    for (int o = 0; o < OUT; o++) {
        float part = hid * W1[lane * OUT + o];
#pragma unroll
        for (int m = 32; m >= 1; m >>= 1) part += __shfl_xor(part, m, 64);
        if (lane == 0) out[g * OUT + o] = part + b1[o];
    }
}

extern "C" void kernel_launch(void* const* d_in, const int* in_sizes, int n_in,
                              void* d_out, int out_size, void* d_ws, size_t ws_size,
                              hipStream_t stream) {
    const float* x     = (const float*)d_in[0];
    const int*   ei    = (const int*)d_in[1];
    const int*   batch = (const int*)d_in[2];
    const float* W1r = (const float*)d_in[3];
    const float* b1  = (const float*)d_in[4];
    const float* W1o = (const float*)d_in[5];
    const float* W2r = (const float*)d_in[6];
    const float* b2  = (const float*)d_in[7];
    const float* W2o = (const float*)d_in[8];
    const float* W3r = (const float*)d_in[9];
    const float* b3  = (const float*)d_in[10];
    const float* W3o = (const float*)d_in[11];
    const float* a1  = (const float*)d_in[12];
    const float* a2  = (const float*)d_in[13];
    const float* Wl0 = (const float*)d_in[14];
    const float* bl0 = (const float*)d_in[15];
    const float* Wl1 = (const float*)d_in[16];
    const float* bl1 = (const float*)d_in[17];

    int N = in_sizes[0] / FDIM;
    int E = in_sizes[1] / 2;
    int OUT = in_sizes[17];
    int G = out_size / OUT;
    int nb = (N + 255) >> NBK_SHIFT;          // 256-node buckets

    const int* src = ei;
    const int* dst = ei + E;

    // workspace layout ([bcount|sums] contiguous for one memset)
    char* w = (char*)d_ws;
    int* rowstart = (int*)w;              w += align_up((size_t)(N + 1) * 4);
    int* adj      = (int*)w;              w += align_up((size_t)E * 4 + 256);
    uint32* ebuf  = (uint32*)w;           w += align_up((size_t)E * 4);
    int* bbase    = (int*)w;              w += align_up((size_t)(nb + 1) * 4);
    int* bcursor  = (int*)w;              w += align_up((size_t)nb * 4);
    ushort16* xbf = (ushort16*)w;         w += align_up((size_t)N * FDIM * 2);
    ushort16* hb1 = (ushort16*)w;         w += align_up((size_t)N * FDIM * 2);
    ushort16* hb2 = (ushort16*)w;         w += align_up((size_t)N * FDIM * 2);
    char* zbase   = w;
    int* bcount   = (int*)w;              w += align_up(512 * 4);
    float* sums   = (float*)w;            w += align_up((size_t)G * FDIM * 4);

    hipMemsetAsync(zbase, 0, (size_t)(w - zbase), stream);

    // CSR build (radix pass with LDS write-regrouping); bhist also converts x
    k_bhist<<<512, 256, 0, stream>>>(dst, bcount, E, nb, x, xbf, (long)N * FDIM / 4);
    k_bscan<<<1, 512, 0, stream>>>(bcount, bbase, bcursor, nb, rowstart, N, E);
    int nchunks = (E + CHUNK - 1) / CHUNK;
    k_bgroup<<<nchunks, 1024, 0, stream>>>(src, dst, bcursor, ebuf, E, nb);
    k_blocal<<<nb, 512, 0, stream>>>(ebuf, bbase, rowstart, adj, N);

    // MFMA fused layers: 16 waves/block, 1 tile/wave (measured-best shape);
    // layer 3 writes into hb1 (dead after layer 2)
    int ntiles = (N + 15) / 16;
    int layerGrid = (ntiles + 15) / 16;        // 391 blocks of 1024 threads
    k_layer<<<layerGrid, 1024, 0, stream>>>(xbf, rowstart, adj, W1r, W1o, b1, a1, hb1, N, 1);
    k_layer<<<layerGrid, 1024, 0, stream>>>(hb1, rowstart, adj, W2r, W2o, b2, a2, hb2, N, 1);
    k_layer<<<layerGrid, 1024, 0, stream>>>(hb2, rowstart, adj, W3r, W3o, b3, nullptr, hb1, N, 0);

    // mean pool + head (cnt via binary search on sorted batch)
    int poolWaves = (N + POOL_CHUNK - 1) / POOL_CHUNK;
    int poolGrid = (poolWaves + 3) / 4;
    k_pool<<<poolGrid, 256, 0, stream>>>(hb1, batch, sums, N);
    k_head<<<G, 64, 0, stream>>>(sums, batch, N, Wl0, bl0, Wl1, bl1, (float*)d_out, OUT);
}